// Round 14
// baseline (270.596 us; speedup 1.0000x reference)
//
#include <hip/hip_runtime.h>
#include <hip/hip_bf16.h>
#include <math.h>

// ISTFT as a single atomic-free bf16 GEMM over an overlapped row view.
//   out[b][r*256+j] = A_view[b,r] (contiguous 4160 bf16, row stride 1040)
//                     dot Bstack[4160][256]   (see R13 header for derivation)
// R14: GEMM occupancy + locality fix.
//   - BN 128->64: grid (4 N-tiles, 272 M-tiles) = 1088 blocks (~4.25/CU vs 2.1)
//   - N-tile is the FAST grid dim: the 4 blocks sharing an M-tile's A panel
//     (1 MB) dispatch adjacently -> A re-reads hit L2/L3 (FETCH was 160 MB).
//   - per-wave tile 64x32 (acc[4][2]), LDS 12 KB, lower VGPR.

#define BATCH  16
#define TFR    2048
#define NB     513
#define HOP    256
#define OUTLEN 525056
#define RROWS  2051                   // output rows per batch (525056/256)
#define PBR    2054                   // padded rows per batch: 3 + 2048 + 3
#define FSTR   1040                   // bf16 elems per padded frame row
#define KTOT   (4 * FSTR)             // 4160
#define BK     32
#define NKT    (KTOT / BK)            // 130
#define KVAL   1026                   // valid elems per frame row
#define MT     17                     // ceil(2051/128) M-tiles per batch
#define TOTROW (BATCH * PBR + 128)    // 32992 incl. 128 slack rows (OOB-read guard)
#define CHPR   (FSTR / 8)             // 130 8-elem chunks per row

typedef __attribute__((ext_vector_type(4))) float f32x4;
typedef __attribute__((ext_vector_type(8))) short bf16x8;

__device__ __forceinline__ void load_lds16(const void* g, void* l)
{
    __builtin_amdgcn_global_load_lds((const __attribute__((address_space(1))) void*)g,
                                     (__attribute__((address_space(3))) void*)l,
                                     16, 0, 0);
}

#define STEP 6.13592315e-3f           // 2*pi/1024

// ---- Bstack, stored transposed: Bg[j][k], k contiguous (row stride KTOT) ----
__global__ __launch_bounds__(256)
void build_B(__hip_bfloat16* __restrict__ Bg)
{
    __shared__ float cosT[1024];
    __shared__ float sinT[1024];
    const int j = blockIdx.x;
    for (int i = threadIdx.x; i < 1024; i += 256) {
        float s, c;
        sincosf((float)i * STEP, &s, &c);
        cosT[i] = c; sinT[i] = s;
    }
    __syncthreads();

    for (int k = threadIdx.x; k < KTOT; k += 256) {
        const int d  = k / FSTR;
        const int kk = k - d * FSTR;
        float val = 0.f;
        if (kk < KVAL) {
            const int   f   = kk >> 1;
            const int   n   = 768 - 256 * d + j;              // 0..1023
            const float syn = (0.5f - 0.5f * cosT[n]) * 0.8660254f * (1.0f / 1024.0f);
            const int   idx = (n * f) & 1023;
            if ((kk & 1) == 0) {
                const float wr = (f == 0 || f == 512) ? 1.f : 2.f;
                val = wr * cosT[idx] * syn;
            } else {
                val = -2.f * sinT[idx] * syn;
            }
        }
        Bg[(size_t)j * KTOT + k] = __float2bfloat16(val);
    }
}

// ---- convert: stfts fp32 -> Ab bf16 padded layout (see R13) ----
__global__ __launch_bounds__(256)
void convert_A(const float* __restrict__ A, __hip_bfloat16* __restrict__ Ab)
{
    const int idx = blockIdx.x * 256 + threadIdx.x;
    if (idx >= TOTROW * CHPR) return;
    const int row = idx / CHPR;
    const int c8  = (idx - row * CHPR) * 8;

    const int b  = row / PBR;                 // >=16 -> slack
    const int rr = row - b * PBR;
    const bool valid = (b < BATCH) && (rr >= 3) && (rr < 3 + TFR);

    union { bf16x8 v; __hip_bfloat162 h[4]; } u;
    if (valid) {
        const int t = rr - 3;
        const float* src = A + (size_t)(b * TFR + t) * KVAL + c8;
        #pragma unroll
        for (int j = 0; j < 8; j += 2) {
            float2 p = make_float2(0.f, 0.f);
            if (c8 + j < KVAL)                // KVAL even: pair all-or-nothing
                p = *reinterpret_cast<const float2*>(src + j);
            u.h[j >> 1] = __float22bfloat162_rn(p);
        }
    } else {
        #pragma unroll
        for (int j = 0; j < 4; ++j) u.h[j] = __float22bfloat162_rn(make_float2(0.f, 0.f));
    }
    *reinterpret_cast<bf16x8*>(Ab + (size_t)row * FSTR + c8) = u.v;
}

// ---- GEMM: 128(M) x 64(N) tile, 4 waves (2M x 2N), wave = 64x32, acc[4][2] ----
__global__ __launch_bounds__(256)
void istft_gemm3(const __hip_bfloat16* __restrict__ Ab,
                 const __hip_bfloat16* __restrict__ Bg,
                 float* __restrict__ out)
{
    __shared__ __hip_bfloat16 Asl[128 * BK];   // 8 KB
    __shared__ __hip_bfloat16 Bsl[64 * BK];    // 4 KB

    const int tid  = threadIdx.x;
    const int n0   = blockIdx.x * 64;          // fast dim: 4 N-tiles share A panel
    const int bi   = blockIdx.y;               // 0..271
    const int b    = bi / MT;
    const int rt   = (bi - b * MT) * 128;
    const int lane = tid & 63;
    const int wave = tid >> 6;
    const int wm   = wave >> 1;                // 0..1 (64-row half)
    const int wn   = wave & 1;                 // 0..1 (32-col half)

    f32x4 acc[4][2] = {};

    const int sm = tid >> 2;                   // staging row 0..63
    const int sk = (tid & 3) * 8;              // staging col
    const int fr = lane & 15;
    const int fk = (lane >> 4) * 8;

    const __hip_bfloat16* ga0 = Ab + ((size_t)b * PBR + rt + sm) * FSTR + sk;
    const __hip_bfloat16* ga1 = Ab + ((size_t)b * PBR + rt + 64 + sm) * FSTR + sk;
    const __hip_bfloat16* gb0 = Bg + (size_t)(n0 + sm) * KTOT + sk;

    for (int kt = 0; kt < NKT; ++kt) {
        const int ko = kt * BK;
        load_lds16(ga0 + ko, Asl + tid * 8);
        load_lds16(ga1 + ko, Asl + 2048 + tid * 8);
        load_lds16(gb0 + ko, Bsl + tid * 8);
        __syncthreads();

        bf16x8 a[4], bv[2];
        #pragma unroll
        for (int mi = 0; mi < 4; ++mi)
            a[mi] = *reinterpret_cast<const bf16x8*>(&Asl[(wm * 64 + mi * 16 + fr) * BK + fk]);
        #pragma unroll
        for (int ni = 0; ni < 2; ++ni)
            bv[ni] = *reinterpret_cast<const bf16x8*>(&Bsl[(wn * 32 + ni * 16 + fr) * BK + fk]);

        #pragma unroll
        for (int mi = 0; mi < 4; ++mi)
            #pragma unroll
            for (int ni = 0; ni < 2; ++ni)
                acc[mi][ni] = __builtin_amdgcn_mfma_f32_16x16x32_bf16(
                    a[mi], bv[ni], acc[mi][ni], 0, 0, 0);

        __syncthreads();
    }

    // epilogue: C/D layout col = lane&15, row = (lane>>4)*4 + j; plain stores
    const int cr = (lane >> 4) * 4;
    const int cc = lane & 15;
    #pragma unroll
    for (int mi = 0; mi < 4; ++mi) {
        #pragma unroll
        for (int ni = 0; ni < 2; ++ni) {
            const int col = n0 + wn * 32 + ni * 16 + cc;
            #pragma unroll
            for (int j = 0; j < 4; ++j) {
                const int r = rt + wm * 64 + mi * 16 + cr + j;
                if (r < RROWS)
                    out[(size_t)b * OUTLEN + (size_t)r * 256 + col] = acc[mi][ni][j];
            }
        }
    }
}

extern "C" void kernel_launch(void* const* d_in, const int* in_sizes, int n_in,
                              void* d_out, int out_size, void* d_ws, size_t ws_size,
                              hipStream_t stream)
{
    const float* A = reinterpret_cast<const float*>(d_in[0]);
    float* out = reinterpret_cast<float*>(d_out);

    const size_t abBytes = (size_t)TOTROW * FSTR * sizeof(__hip_bfloat16); // 68.62 MB
    __hip_bfloat16* Ab = reinterpret_cast<__hip_bfloat16*>(d_ws);
    __hip_bfloat16* Bg = reinterpret_cast<__hip_bfloat16*>((char*)d_ws + abBytes); // +2.13 MB

    build_B<<<dim3(256), dim3(256), 0, stream>>>(Bg);

    const int nChunks = TOTROW * CHPR;                       // 4,288,960
    convert_A<<<dim3((nChunks + 255) / 256), dim3(256), 0, stream>>>(A, Ab);

    istft_gemm3<<<dim3(4, BATCH * MT), dim3(256), 0, stream>>>(Ab, Bg, out);
}

// Round 15
// 217.914 us; speedup vs baseline: 1.2418x; 1.2418x over previous
//
#include <hip/hip_runtime.h>
#include <hip/hip_bf16.h>
#include <math.h>

// ISTFT as a single atomic-free bf16 GEMM over an overlapped row view.
//   out[b][r*256+j] = A_view[b,r] (contiguous 4160 bf16, row stride 1040)
//                     dot Bstack[4160][256]   (see R13 header for derivation)
// R15: R14 + XCD-aware work remap. R14's N-fast grid put the 4 blocks sharing
//   an A-panel on 4 DIFFERENT XCDs (round-robin dispatch) -> 605 MB FETCH,
//   HBM-bound. Remap (1088 = 8 x 136): xcd = wg%8, slot = wg/8,
//   mt = xcd*34 + slot/4, nt = slot%4  -> the 4 sharers get ids {x,x+8,x+16,
//   x+24}: same XCD, near-simultaneous -> one L2 fetch serves 4; each M-tile
//   owned by exactly one XCD -> A fetched ~once (68 MB).

#define BATCH  16
#define TFR    2048
#define NB     513
#define HOP    256
#define OUTLEN 525056
#define RROWS  2051                   // output rows per batch (525056/256)
#define PBR    2054                   // padded rows per batch: 3 + 2048 + 3
#define FSTR   1040                   // bf16 elems per padded frame row
#define KTOT   (4 * FSTR)             // 4160
#define BK     32
#define NKT    (KTOT / BK)            // 130
#define KVAL   1026                   // valid elems per frame row
#define MT     17                     // ceil(2051/128) M-tiles per batch
#define MTOT   (BATCH * MT)           // 272 M-tiles total = 8 XCDs * 34
#define TOTROW (BATCH * PBR + 128)    // 32992 incl. 128 slack rows (OOB-read guard)
#define CHPR   (FSTR / 8)             // 130 8-elem chunks per row

typedef __attribute__((ext_vector_type(4))) float f32x4;
typedef __attribute__((ext_vector_type(8))) short bf16x8;

__device__ __forceinline__ void load_lds16(const void* g, void* l)
{
    __builtin_amdgcn_global_load_lds((const __attribute__((address_space(1))) void*)g,
                                     (__attribute__((address_space(3))) void*)l,
                                     16, 0, 0);
}

#define STEP 6.13592315e-3f           // 2*pi/1024

// ---- Bstack, stored transposed: Bg[j][k], k contiguous (row stride KTOT) ----
__global__ __launch_bounds__(256)
void build_B(__hip_bfloat16* __restrict__ Bg)
{
    __shared__ float cosT[1024];
    __shared__ float sinT[1024];
    const int j = blockIdx.x;
    for (int i = threadIdx.x; i < 1024; i += 256) {
        float s, c;
        sincosf((float)i * STEP, &s, &c);
        cosT[i] = c; sinT[i] = s;
    }
    __syncthreads();

    for (int k = threadIdx.x; k < KTOT; k += 256) {
        const int d  = k / FSTR;
        const int kk = k - d * FSTR;
        float val = 0.f;
        if (kk < KVAL) {
            const int   f   = kk >> 1;
            const int   n   = 768 - 256 * d + j;              // 0..1023
            const float syn = (0.5f - 0.5f * cosT[n]) * 0.8660254f * (1.0f / 1024.0f);
            const int   idx = (n * f) & 1023;
            if ((kk & 1) == 0) {
                const float wr = (f == 0 || f == 512) ? 1.f : 2.f;
                val = wr * cosT[idx] * syn;
            } else {
                val = -2.f * sinT[idx] * syn;
            }
        }
        Bg[(size_t)j * KTOT + k] = __float2bfloat16(val);
    }
}

// ---- convert: stfts fp32 -> Ab bf16 padded layout (see R13) ----
__global__ __launch_bounds__(256)
void convert_A(const float* __restrict__ A, __hip_bfloat16* __restrict__ Ab)
{
    const int idx = blockIdx.x * 256 + threadIdx.x;
    if (idx >= TOTROW * CHPR) return;
    const int row = idx / CHPR;
    const int c8  = (idx - row * CHPR) * 8;

    const int b  = row / PBR;                 // >=16 -> slack
    const int rr = row - b * PBR;
    const bool valid = (b < BATCH) && (rr >= 3) && (rr < 3 + TFR);

    union { bf16x8 v; __hip_bfloat162 h[4]; } u;
    if (valid) {
        const int t = rr - 3;
        const float* src = A + (size_t)(b * TFR + t) * KVAL + c8;
        #pragma unroll
        for (int j = 0; j < 8; j += 2) {
            float2 p = make_float2(0.f, 0.f);
            if (c8 + j < KVAL)                // KVAL even: pair all-or-nothing
                p = *reinterpret_cast<const float2*>(src + j);
            u.h[j >> 1] = __float22bfloat162_rn(p);
        }
    } else {
        #pragma unroll
        for (int j = 0; j < 4; ++j) u.h[j] = __float22bfloat162_rn(make_float2(0.f, 0.f));
    }
    *reinterpret_cast<bf16x8*>(Ab + (size_t)row * FSTR + c8) = u.v;
}

// ---- GEMM: 128(M) x 64(N) tile, 4 waves (2M x 2N), wave = 64x32, acc[4][2] ----
__global__ __launch_bounds__(256)
void istft_gemm4(const __hip_bfloat16* __restrict__ Ab,
                 const __hip_bfloat16* __restrict__ Bg,
                 float* __restrict__ out)
{
    __shared__ __hip_bfloat16 Asl[128 * BK];   // 8 KB
    __shared__ __hip_bfloat16 Bsl[64 * BK];    // 4 KB

    const int tid  = threadIdx.x;

    // XCD-aware remap: 1088 blocks = 8 XCDs x (34 M-tiles x 4 N-tiles)
    const int wg   = blockIdx.x;
    const int xcd  = wg & 7;                   // dispatch round-robins ids % 8
    const int slot = wg >> 3;                  // 0..135, in dispatch order per XCD
    const int mtg  = xcd * 34 + (slot >> 2);   // global M-tile 0..271
    const int nt   = slot & 3;

    const int b    = mtg / MT;
    const int rt   = (mtg - b * MT) * 128;
    const int n0   = nt * 64;

    const int lane = tid & 63;
    const int wave = tid >> 6;
    const int wm   = wave >> 1;                // 0..1 (64-row half)
    const int wn   = wave & 1;                 // 0..1 (32-col half)

    f32x4 acc[4][2] = {};

    const int sm = tid >> 2;                   // staging row 0..63
    const int sk = (tid & 3) * 8;              // staging col
    const int fr = lane & 15;
    const int fk = (lane >> 4) * 8;

    const __hip_bfloat16* ga0 = Ab + ((size_t)b * PBR + rt + sm) * FSTR + sk;
    const __hip_bfloat16* ga1 = Ab + ((size_t)b * PBR + rt + 64 + sm) * FSTR + sk;
    const __hip_bfloat16* gb0 = Bg + (size_t)(n0 + sm) * KTOT + sk;

    for (int kt = 0; kt < NKT; ++kt) {
        const int ko = kt * BK;
        load_lds16(ga0 + ko, Asl + tid * 8);
        load_lds16(ga1 + ko, Asl + 2048 + tid * 8);
        load_lds16(gb0 + ko, Bsl + tid * 8);
        __syncthreads();

        bf16x8 a[4], bv[2];
        #pragma unroll
        for (int mi = 0; mi < 4; ++mi)
            a[mi] = *reinterpret_cast<const bf16x8*>(&Asl[(wm * 64 + mi * 16 + fr) * BK + fk]);
        #pragma unroll
        for (int ni = 0; ni < 2; ++ni)
            bv[ni] = *reinterpret_cast<const bf16x8*>(&Bsl[(wn * 32 + ni * 16 + fr) * BK + fk]);

        #pragma unroll
        for (int mi = 0; mi < 4; ++mi)
            #pragma unroll
            for (int ni = 0; ni < 2; ++ni)
                acc[mi][ni] = __builtin_amdgcn_mfma_f32_16x16x32_bf16(
                    a[mi], bv[ni], acc[mi][ni], 0, 0, 0);

        __syncthreads();
    }

    // epilogue: C/D layout col = lane&15, row = (lane>>4)*4 + j; plain stores
    const int cr = (lane >> 4) * 4;
    const int cc = lane & 15;
    #pragma unroll
    for (int mi = 0; mi < 4; ++mi) {
        #pragma unroll
        for (int ni = 0; ni < 2; ++ni) {
            const int col = n0 + wn * 32 + ni * 16 + cc;
            #pragma unroll
            for (int j = 0; j < 4; ++j) {
                const int r = rt + wm * 64 + mi * 16 + cr + j;
                if (r < RROWS)
                    out[(size_t)b * OUTLEN + (size_t)r * 256 + col] = acc[mi][ni][j];
            }
        }
    }
}

extern "C" void kernel_launch(void* const* d_in, const int* in_sizes, int n_in,
                              void* d_out, int out_size, void* d_ws, size_t ws_size,
                              hipStream_t stream)
{
    const float* A = reinterpret_cast<const float*>(d_in[0]);
    float* out = reinterpret_cast<float*>(d_out);

    const size_t abBytes = (size_t)TOTROW * FSTR * sizeof(__hip_bfloat16); // 68.62 MB
    __hip_bfloat16* Ab = reinterpret_cast<__hip_bfloat16*>(d_ws);
    __hip_bfloat16* Bg = reinterpret_cast<__hip_bfloat16*>((char*)d_ws + abBytes); // +2.13 MB

    build_B<<<dim3(256), dim3(256), 0, stream>>>(Bg);

    const int nChunks = TOTROW * CHPR;                       // 4,288,960
    convert_A<<<dim3((nChunks + 255) / 256), dim3(256), 0, stream>>>(A, Ab);

    istft_gemm4<<<dim3(MTOT * 4), dim3(256), 0, stream>>>(Ab, Bg, out);
}